// Round 3
// baseline (400.596 us; speedup 1.0000x reference)
//
#include <hip/hip_runtime.h>

#define SEG 24
#define DD  32
#define PD  8            // dims per lane (4 lanes per item)
#define HEPS 1e-7f
#define N_ITERS 10

__device__ __forceinline__ float frcp(float x) { return __builtin_amdgcn_rcpf(x); }

// quad_perm [1,0,3,2] -> xor1 ; [2,3,0,1] -> xor2 ; pure-VALU cross-lane
__device__ __forceinline__ float qx1(float x) {
    return __int_as_float(__builtin_amdgcn_mov_dpp(__float_as_int(x), 0xB1, 0xF, 0xF, true));
}
__device__ __forceinline__ float qx2(float x) {
    return __int_as_float(__builtin_amdgcn_mov_dpp(__float_as_int(x), 0x4E, 0xF, 0xF, true));
}
__device__ __forceinline__ float qsum(float x) {   // sum over the 4 lanes of a quad
    x += qx1(x);
    x += qx2(x);
    return x;
}

// coef = arccosh(alpha)/sqrt(alpha^2-1), caller guarantees alpha >= 1+1e-7
__device__ __forceinline__ float acosh_coef(float alpha) {
    float am = fmaf(alpha, alpha, -1.0f);
    float s  = sqrtf(am);
    return __logf(alpha + s) * frcp(s);
}

__global__ __launch_bounds__(256, 4)
void slmw_kernel(const float* __restrict__ x0, const float* __restrict__ x1,
                 const float* __restrict__ x2, const float* __restrict__ x3,
                 const float* __restrict__ W0, const float* __restrict__ b0,
                 const float* __restrict__ W1, const float* __restrict__ b1,
                 const float* __restrict__ W2, const float* __restrict__ b2,
                 const float* __restrict__ W3, const float* __restrict__ b3,
                 const float* __restrict__ es, const float* __restrict__ lw,
                 float* __restrict__ out, int n_items)
{
    const int t    = blockIdx.x * blockDim.x + threadIdx.x;
    const int item = t >> 2;
    const int sub  = t & 3;
    if (item >= n_items) return;

    const float m0 = (sub == 0) ? 1.0f : 0.0f;   // this lane owns the time dim d=0

    const float ts = tanhf(es[0]);

    float l0 = lw[0], l1 = lw[1], l2 = lw[2], l3 = lw[3];
    float mx = fmaxf(fmaxf(l0, l1), fmaxf(l2, l3));
    float e0 = __expf(l0 - mx), e1 = __expf(l1 - mx),
          e2 = __expf(l2 - mx), e3 = __expf(l3 - mx);
    float inv = frcp(e0 + e1 + e2 + e3);
    float w4[4] = { e0 * inv, e1 * inv, e2 * inv, e3 * inv };

    const float* xs[4] = { x0, x1, x2, x3 };
    const float* Ws[4] = { W0, W1, W2, W3 };
    const float* bs[4] = { b0, b1, b2, b3 };

    const size_t base = (size_t)item * SEG;
    const size_t osz  = (size_t)n_items * DD;
    const int    doff = sub * PD;

    float h[4][PD];

    // ---- encode + to_hyperbolic per stream ----
    #pragma unroll
    for (int s = 0; s < 4; ++s) {
        const float4* sp = reinterpret_cast<const float4*>(xs[s] + base);
        float seg[SEG];
        #pragma unroll
        for (int j = 0; j < SEG / 4; ++j) {
            float4 v = sp[j];
            seg[4*j+0] = v.x; seg[4*j+1] = v.y; seg[4*j+2] = v.z; seg[4*j+3] = v.w;
        }

        const float* wbase = Ws[s] + (size_t)doff * SEG;
        float4 bA = reinterpret_cast<const float4*>(bs[s] + doff)[0];
        float4 bB = reinterpret_cast<const float4*>(bs[s] + doff)[1];
        float bb[PD] = { bA.x, bA.y, bA.z, bA.w, bB.x, bB.y, bB.z, bB.w };

        float u[PD];
        #pragma unroll
        for (int j = 0; j < PD; ++j) {
            const float4* wp = reinterpret_cast<const float4*>(wbase + j * SEG);
            float acc = bb[j];
            #pragma unroll
            for (int q = 0; q < SEG / 4; ++q) {
                float4 w = wp[q];
                acc = fmaf(seg[4*q+0], w.x, acc);
                acc = fmaf(seg[4*q+1], w.y, acc);
                acc = fmaf(seg[4*q+2], w.z, acc);
                acc = fmaf(seg[4*q+3], w.w, acc);
            }
            u[j] = acc * ts;
        }

        // safe_expmap0: <u,u>_L partial = sum(u^2) with -2*u0^2 on the time lane
        float a = 0.0f;
        #pragma unroll
        for (int j = 0; j < PD; ++j) a = fmaf(u[j], u[j], a);
        a = fmaf(-2.0f * u[0] * u[0], m0, a);
        float sq  = fmaxf(qsum(a), 1e-12f);
        float nrm = sqrtf(sq);
        float ep  = __expf(nrm), em = frcp(ep);
        float sh  = 0.5f * (ep - em);
        float sc  = sh * frcp(fmaxf(nrm, HEPS));

        float y[PD];
        float b2 = 0.0f;
        #pragma unroll
        for (int j = 0; j < PD; ++j) {
            y[j] = sc * u[j];
            b2   = fmaf(y[j], y[j], b2);
        }
        b2 = fmaf(-y[0] * y[0], m0, b2);        // space-norm excludes d=0
        float ss    = qsum(b2);
        float tcomp = sqrtf(1.0f + ss);         // projx time component
        y[0] = (sub == 0) ? tcomp : y[0];

        float* op = out + (size_t)s * osz + (size_t)item * DD + doff;
        reinterpret_cast<float4*>(op)[0] = make_float4(y[0], y[1], y[2], y[3]);
        reinterpret_cast<float4*>(op)[1] = make_float4(y[4], y[5], y[6], y[7]);

        #pragma unroll
        for (int j = 0; j < PD; ++j) h[s][j] = y[j];
    }

    // ---- fusion init: t0 = sum_s w_s*logmap0(h_s); mean = projx(expmap0(t0)) ----
    float mean[PD];
    {
        float t0[PD];
        #pragma unroll
        for (int j = 0; j < PD; ++j) t0[j] = 0.0f;

        #pragma unroll
        for (int s = 0; s < 4; ++s) {
            float y0    = qsum(m0 * h[s][0]);             // broadcast time comp
            float alpha = fmaxf(y0, 1.0f + HEPS);
            float c     = w4[s] * acosh_coef(alpha);
            t0[0] = fmaf(c, h[s][0] - m0 * alpha, t0[0]); // time lane: c*(y0-alpha)
            #pragma unroll
            for (int j = 1; j < PD; ++j) t0[j] = fmaf(c, h[s][j], t0[j]);
        }

        float a = 0.0f;
        #pragma unroll
        for (int j = 0; j < PD; ++j) a = fmaf(t0[j], t0[j], a);
        a = fmaf(-2.0f * t0[0] * t0[0], m0, a);
        float sq  = fmaxf(qsum(a), 1e-12f);
        float nrm = sqrtf(sq);
        float ep  = __expf(nrm), em = frcp(ep);
        float sh  = 0.5f * (ep - em);
        float sc  = sh * frcp(fmaxf(nrm, HEPS));

        float b2 = 0.0f;
        #pragma unroll
        for (int j = 0; j < PD; ++j) {
            mean[j] = sc * t0[j];
            b2      = fmaf(mean[j], mean[j], b2);
        }
        b2 = fmaf(-mean[0] * mean[0], m0, b2);
        float ss    = qsum(b2);
        float tcomp = sqrtf(1.0f + ss);
        mean[0] = (sub == 0) ? tcomp : mean[0];
    }

    // ---- Frechet refinement (global early-exit dropped: sub-tolerance drift) ----
    for (int it = 0; it < N_ITERS; ++it) {
        float wv[PD];
        #pragma unroll
        for (int j = 0; j < PD; ++j) wv[j] = 0.0f;

        #pragma unroll
        for (int s = 0; s < 4; ++s) {
            float a = 0.0f;
            #pragma unroll
            for (int j = 0; j < PD; ++j) a = fmaf(mean[j], h[s][j], a);
            a = fmaf(-2.0f * mean[0] * h[s][0], m0, a);    // partial of <m,h>_L
            float inner = qsum(a);
            float alpha = fmaxf(-inner, 1.0f + HEPS);
            float c     = w4[s] * acosh_coef(alpha);
            #pragma unroll
            for (int j = 0; j < PD; ++j)
                wv[j] = fmaf(c, fmaf(-alpha, mean[j], h[s][j]), wv[j]);
        }

        // u = 0.5*wv ; mean = projx(cosh(n)*mean + sinh(n)*u/max(n,eps))
        float a = 0.0f;
        #pragma unroll
        for (int j = 0; j < PD; ++j) a = fmaf(wv[j], wv[j], a);
        a = fmaf(-2.0f * wv[0] * wv[0], m0, a);
        float sq  = fmaxf(0.25f * qsum(a), 1e-12f);
        float nrm = sqrtf(sq);
        float ep  = __expf(nrm), em = frcp(ep);
        float ch  = 0.5f * (ep + em);
        float sh  = 0.5f * (ep - em);
        float sc  = 0.5f * sh * frcp(fmaxf(nrm, HEPS));

        float y[PD];
        float b2 = 0.0f;
        #pragma unroll
        for (int j = 0; j < PD; ++j) {
            y[j] = fmaf(ch, mean[j], sc * wv[j]);
            b2   = fmaf(y[j], y[j], b2);
        }
        b2 = fmaf(-y[0] * y[0], m0, b2);
        float ss    = qsum(b2);
        float tcomp = sqrtf(1.0f + ss);
        mean[0] = (sub == 0) ? tcomp : y[0];
        #pragma unroll
        for (int j = 1; j < PD; ++j) mean[j] = y[j];
    }

    float* op = out + (size_t)4 * osz + (size_t)item * DD + doff;
    reinterpret_cast<float4*>(op)[0] = make_float4(mean[0], mean[1], mean[2], mean[3]);
    reinterpret_cast<float4*>(op)[1] = make_float4(mean[4], mean[5], mean[6], mean[7]);
}

extern "C" void kernel_launch(void* const* d_in, const int* in_sizes, int n_in,
                              void* d_out, int out_size, void* d_ws, size_t ws_size,
                              hipStream_t stream)
{
    const float* x0 = (const float*)d_in[0];
    const float* x1 = (const float*)d_in[1];
    const float* x2 = (const float*)d_in[2];
    const float* x3 = (const float*)d_in[3];
    const float* W0 = (const float*)d_in[4];
    const float* b0 = (const float*)d_in[5];
    const float* W1 = (const float*)d_in[6];
    const float* b1 = (const float*)d_in[7];
    const float* W2 = (const float*)d_in[8];
    const float* b2 = (const float*)d_in[9];
    const float* W3 = (const float*)d_in[10];
    const float* b3 = (const float*)d_in[11];
    const float* es = (const float*)d_in[12];
    const float* lw = (const float*)d_in[13];

    const int n_items   = in_sizes[0] / SEG;     // 262144
    const int n_threads = n_items * 4;           // 4 lanes per item
    const int block = 256;
    const int grid  = (n_threads + block - 1) / block;

    slmw_kernel<<<grid, block, 0, stream>>>(x0, x1, x2, x3,
                                            W0, b0, W1, b1, W2, b2, W3, b3,
                                            es, lw, (float*)d_out, n_items);
}